// Round 1
// baseline (134.332 us; speedup 1.0000x reference)
//
#include <hip/hip_runtime.h>

// Problem: out[b,n] = relu( sum_d x[b, idx[n,d]] * w[n,d] )
//   x: (B=256, N=16384) f32, w: (N, DEG=32) f32, idx: (N, DEG) i32, out: (B, N) f32
//
// Strategy:
//   K1: transpose x (B x N) -> xT (N x B) in d_ws, so gathered "columns" of x
//       become contiguous 1 KiB rows (coalesced wave loads).
//   K2: each block handles NT=32 consecutive n. Stage idx/w for the tile in LDS,
//       each wave computes 8 n's with lane l owning float4 of b = 4l..4l+3.
//       Epilogue transposes the 256x32 out tile through padded LDS so global
//       stores are 128 B contiguous segments.

#define B    256
#define N    16384
#define DEG  32
#define NT   32          // n per block in K2
#define BPAD 260         // padded b-stride (floats) for LDS out tile: 260 % 32 == 4, 65-style pad

__global__ __launch_bounds__(256) void transpose_x_kernel(
    const float* __restrict__ x, float* __restrict__ xT) {
    __shared__ float tile[64][65];   // +1 pad breaks bank conflicts on transposed read
    const int t  = threadIdx.x;
    const int j0 = blockIdx.x * 64;  // N/64 = 256 tiles
    const int b0 = blockIdx.y * 64;  // B/64 = 4 tiles
    const int c4 = t & 15;           // float4 column within tile
    const int r  = t >> 4;           // row 0..15

#pragma unroll
    for (int it = 0; it < 4; ++it) {
        const int row = r + it * 16;                       // b offset in tile
        const float4 v = *(const float4*)&x[(size_t)(b0 + row) * N + j0 + c4 * 4];
        tile[row][c4 * 4 + 0] = v.x;
        tile[row][c4 * 4 + 1] = v.y;
        tile[row][c4 * 4 + 2] = v.z;
        tile[row][c4 * 4 + 3] = v.w;
    }
    __syncthreads();
#pragma unroll
    for (int it = 0; it < 4; ++it) {
        const int row = r + it * 16;                       // j offset in tile
        float4 v;
        v.x = tile[c4 * 4 + 0][row];
        v.y = tile[c4 * 4 + 1][row];
        v.z = tile[c4 * 4 + 2][row];
        v.w = tile[c4 * 4 + 3][row];
        *(float4*)&xT[(size_t)(j0 + row) * B + b0 + c4 * 4] = v;
    }
}

__global__ __launch_bounds__(256) void gather_dot_kernel(
    const float* __restrict__ xT, const float* __restrict__ w,
    const int* __restrict__ idx, float* __restrict__ out) {
    // LDS: first used as idx/w staging (NT*DEG ints + NT*DEG floats = 16 KiB of
    // the buffer), then (after barrier) reused as the padded output tile.
    __shared__ __align__(16) float smem[NT * BPAD];        // 33,280 B
    int*   sidx = (int*)smem;                              // [NT*DEG] = 1024 ints
    float* sw   = smem + NT * DEG;                         // [NT*DEG] = 1024 floats

    const int t   = threadIdx.x;
    const int nb  = blockIdx.x * NT;                       // block's n base
    const int wv  = t >> 6;                                // wave 0..3
    const int l   = t & 63;                                // lane

    // Stage idx/w for rows nb..nb+NT (contiguous NT*DEG region), coalesced.
    {
        const int4   iv = *(const int4*)&idx[(size_t)nb * DEG + t * 4];
        const float4 wf = *(const float4*)&w[(size_t)nb * DEG + t * 4];
        ((int4*)sidx)[t] = iv;
        ((float4*)sw)[t] = wf;
    }
    __syncthreads();

    // Each wave owns 8 n's; lane owns b = 4l..4l+3 as float4.
    float4 acc[8];
#pragma unroll
    for (int i = 0; i < 8; ++i) acc[i] = make_float4(0.f, 0.f, 0.f, 0.f);

    const int nl0 = wv * 8;
    const float* xTl = xT + 4 * l;                          // lane's b offset

#pragma unroll
    for (int i = 0; i < 8; ++i) {
        const int nl = nl0 + i;
#pragma unroll
        for (int d4 = 0; d4 < DEG / 4; ++d4) {
            // wave-uniform b128 broadcast reads from LDS (conflict-free)
            const int4   j4 = ((const int4*)sidx)[nl * (DEG / 4) + d4];
            const float4 w4 = ((const float4*)sw)[nl * (DEG / 4) + d4];
            const float4 v0 = *(const float4*)&xTl[(size_t)j4.x * B];
            const float4 v1 = *(const float4*)&xTl[(size_t)j4.y * B];
            const float4 v2 = *(const float4*)&xTl[(size_t)j4.z * B];
            const float4 v3 = *(const float4*)&xTl[(size_t)j4.w * B];
            acc[i].x = fmaf(w4.x, v0.x, acc[i].x);
            acc[i].y = fmaf(w4.x, v0.y, acc[i].y);
            acc[i].z = fmaf(w4.x, v0.z, acc[i].z);
            acc[i].w = fmaf(w4.x, v0.w, acc[i].w);
            acc[i].x = fmaf(w4.y, v1.x, acc[i].x);
            acc[i].y = fmaf(w4.y, v1.y, acc[i].y);
            acc[i].z = fmaf(w4.y, v1.z, acc[i].z);
            acc[i].w = fmaf(w4.y, v1.w, acc[i].w);
            acc[i].x = fmaf(w4.z, v2.x, acc[i].x);
            acc[i].y = fmaf(w4.z, v2.y, acc[i].y);
            acc[i].z = fmaf(w4.z, v2.z, acc[i].z);
            acc[i].w = fmaf(w4.z, v2.w, acc[i].w);
            acc[i].x = fmaf(w4.w, v3.x, acc[i].x);
            acc[i].y = fmaf(w4.w, v3.y, acc[i].y);
            acc[i].z = fmaf(w4.w, v3.z, acc[i].z);
            acc[i].w = fmaf(w4.w, v3.w, acc[i].w);
        }
    }

    __syncthreads();   // staging dead; reuse smem as out tile [n][b] padded

    // Write acc to LDS tile: smem[nl*BPAD + b], float4 at b=4l (16B-aligned since BPAD%4==0)
#pragma unroll
    for (int i = 0; i < 8; ++i) {
        *(float4*)&smem[(nl0 + i) * BPAD + 4 * l] = acc[i];
    }
    __syncthreads();

    // Transposed store: wave wv owns b rows [wv*64, wv*64+64).
    // Lane covers (b_row = l>>3, n0 = (l&7)*4): 8 b-rows x 32 n per wave-store,
    // 128 B contiguous per b-row.
    const int n0 = (l & 7) * 4;
#pragma unroll
    for (int r = 0; r < 8; ++r) {
        const int b = wv * 64 + r * 8 + (l >> 3);
        float4 v;
        v.x = smem[(n0 + 0) * BPAD + b];
        v.y = smem[(n0 + 1) * BPAD + b];
        v.z = smem[(n0 + 2) * BPAD + b];
        v.w = smem[(n0 + 3) * BPAD + b];
        v.x = fmaxf(v.x, 0.f);
        v.y = fmaxf(v.y, 0.f);
        v.z = fmaxf(v.z, 0.f);
        v.w = fmaxf(v.w, 0.f);
        *(float4*)&out[(size_t)b * N + nb + n0] = v;
    }
}

extern "C" void kernel_launch(void* const* d_in, const int* in_sizes, int n_in,
                              void* d_out, int out_size, void* d_ws, size_t ws_size,
                              hipStream_t stream) {
    const float* x   = (const float*)d_in[0];   // (B, N)
    const float* w   = (const float*)d_in[1];   // (N, DEG)
    const int*   idx = (const int*)d_in[2];     // (N, DEG)
    float* out = (float*)d_out;                 // (B, N)
    float* xT  = (float*)d_ws;                  // (N, B) = 16 MiB scratch

    dim3 tgrid(N / 64, B / 64);                 // 256 x 4 blocks
    transpose_x_kernel<<<tgrid, 256, 0, stream>>>(x, xT);

    gather_dot_kernel<<<N / NT, 256, 0, stream>>>(xT, w, idx, out);
}

// Round 2
// 98.949 us; speedup vs baseline: 1.3576x; 1.3576x over previous
//
#include <hip/hip_runtime.h>

// out[b,n] = relu( sum_d x[b, idx[n,d]] * w[n,d] )
//   x: (B=256, N=16384) f32, w: (N,32) f32, idx: (N,32) i32, out: (B,N) f32
//
// R2 strategy:
//   K1: x (B x N) -> xc[chunk][N][32] where chunk = b/32. Each chunk is 2 MiB,
//       small enough to live in one XCD's 4 MiB L2.
//   K2: block = (n-tile of 32) x (one chunk). chunk = blockIdx % 8 so the same
//       chunk pins to the same XCD (round-robin dispatch) -> gathers are L2 hits.
//       Wave-load: 8 j-slots x 128 B contiguous = 1 KiB useful per instruction.
//       Out tile transposed through padded LDS; nontemporal stores keep the
//       16 MiB out stream from evicting the pinned gather set.

#define B      256
#define N      16384
#define DEG    32
#define NT     32        // n per block in K2
#define NCHUNK 8
#define CB     32        // b per chunk

typedef float v4f __attribute__((ext_vector_type(4)));

__global__ __launch_bounds__(256) void chunk_transpose_kernel(
    const float* __restrict__ x, float* __restrict__ xc) {
    __shared__ float tile[64][65];               // [b_local][j_local], +1 pad
    const int t  = threadIdx.x;
    const int j0 = blockIdx.x * 64;              // N/64 = 256
    const int b0 = blockIdx.y * 64;              // B/64 = 4  (covers 2 chunks)
    const int c4 = t & 15;
    const int r  = t >> 4;

#pragma unroll
    for (int it = 0; it < 4; ++it) {
        const int row = r + it * 16;             // b offset in tile
        const float4 v = *(const float4*)&x[(size_t)(b0 + row) * N + j0 + 4 * c4];
        tile[row][4 * c4 + 0] = v.x;
        tile[row][4 * c4 + 1] = v.y;
        tile[row][4 * c4 + 2] = v.z;
        tile[row][4 * c4 + 3] = v.w;
    }
    __syncthreads();

    const int wv = t >> 6, l = t & 63;
    const int cbase = (b0 >> 5) + (l >> 5);      // this lane's chunk
    const int bl    = l & 31;                    // b within chunk
    float* dst = xc + (size_t)cbase * N * CB + bl;
#pragma unroll
    for (int jr = 0; jr < 16; ++jr) {
        const int j = wv * 16 + jr;              // j_local: wave owns 16 rows
        dst[(size_t)(j0 + j) * CB] = tile[l][j]; // LDS bank = (l+j)%32: 2-way, free
    }
}

__global__ __launch_bounds__(256, 8) void gather_dot_kernel(
    const float* __restrict__ xc, const float* __restrict__ w,
    const int* __restrict__ idx, float* __restrict__ out) {
    // 8 KiB: sidx (1024 i32) + sw (1024 f32); reused after the loop as the
    // padded out tile [NT][33] (4224 B).
    __shared__ __align__(16) float smem[2048];
    int*   sidx = (int*)smem;
    float* sw   = smem + NT * DEG;

    const int t     = threadIdx.x;
    const int chunk = blockIdx.x & 7;            // == XCD id under %8 round-robin
    const int nb    = (int)(blockIdx.x >> 3) * NT;
    const int wv    = t >> 6;
    const int l     = t & 63;
    const int slot  = wv * 8 + (l >> 3);         // n_local 0..31 (1 n per thread)
    const int a     = l & 7;                     // b4 group: b_local = 4a..4a+3

    // Stage idx/w for the n-tile (coalesced 16 B/lane).
    ((int4*)sidx)[t]   = ((const int4*)(idx + (size_t)nb * DEG))[t];
    ((float4*)sw)[t]   = ((const float4*)(w   + (size_t)nb * DEG))[t];
    __syncthreads();

    const float* xcb = xc + (size_t)chunk * N * CB + 4 * a;
    const int4*   sidx4 = (const int4*)sidx;
    const float4* sw4   = (const float4*)sw;

    float4 acc = make_float4(0.f, 0.f, 0.f, 0.f);
#pragma unroll
    for (int d4 = 0; d4 < DEG / 4; ++d4) {
        // lanes with equal slot read the same LDS address -> broadcast
        const int4   j4 = sidx4[slot * (DEG / 4) + d4];
        const float4 w4 = sw4[slot * (DEG / 4) + d4];
        // each load: 8 slots x 128 B contiguous segments = 1 KiB/wave-instr, L2-hit
        const float4 v0 = *(const float4*)&xcb[(size_t)j4.x * CB];
        const float4 v1 = *(const float4*)&xcb[(size_t)j4.y * CB];
        const float4 v2 = *(const float4*)&xcb[(size_t)j4.z * CB];
        const float4 v3 = *(const float4*)&xcb[(size_t)j4.w * CB];
        acc.x = fmaf(w4.x, v0.x, acc.x); acc.y = fmaf(w4.x, v0.y, acc.y);
        acc.z = fmaf(w4.x, v0.z, acc.z); acc.w = fmaf(w4.x, v0.w, acc.w);
        acc.x = fmaf(w4.y, v1.x, acc.x); acc.y = fmaf(w4.y, v1.y, acc.y);
        acc.z = fmaf(w4.y, v1.z, acc.z); acc.w = fmaf(w4.y, v1.w, acc.w);
        acc.x = fmaf(w4.z, v2.x, acc.x); acc.y = fmaf(w4.z, v2.y, acc.y);
        acc.z = fmaf(w4.z, v2.z, acc.z); acc.w = fmaf(w4.z, v2.w, acc.w);
        acc.x = fmaf(w4.w, v3.x, acc.x); acc.y = fmaf(w4.w, v3.y, acc.y);
        acc.z = fmaf(w4.w, v3.z, acc.z); acc.w = fmaf(w4.w, v3.w, acc.w);
    }
    __syncthreads();                             // staging dead; reuse as out tile

    float* tile = smem;                          // [NT][33]
    tile[slot * 33 + 4 * a + 0] = acc.x;         // bank (slot+4a+k)%32: <=2-way
    tile[slot * 33 + 4 * a + 1] = acc.y;
    tile[slot * 33 + 4 * a + 2] = acc.z;
    tile[slot * 33 + 4 * a + 3] = acc.w;
    __syncthreads();

    // Wave wv stores b rows wv*8 .. wv*8+7; 128 B contiguous per row.
    const int br = wv * 8 + (l >> 3);            // b within chunk
    const int n0 = 4 * (l & 7);
    v4f v;
    v.x = fmaxf(tile[(n0 + 0) * 33 + br], 0.f);
    v.y = fmaxf(tile[(n0 + 1) * 33 + br], 0.f);
    v.z = fmaxf(tile[(n0 + 2) * 33 + br], 0.f);
    v.w = fmaxf(tile[(n0 + 3) * 33 + br], 0.f);
    __builtin_nontemporal_store(v, (v4f*)&out[(size_t)(chunk * CB + br) * N + nb + n0]);
}

extern "C" void kernel_launch(void* const* d_in, const int* in_sizes, int n_in,
                              void* d_out, int out_size, void* d_ws, size_t ws_size,
                              hipStream_t stream) {
    const float* x   = (const float*)d_in[0];    // (B, N)
    const float* w   = (const float*)d_in[1];    // (N, DEG)
    const int*   idx = (const int*)d_in[2];      // (N, DEG)
    float* out = (float*)d_out;                  // (B, N)
    float* xc  = (float*)d_ws;                   // [8][N][32] = 16 MiB

    dim3 tgrid(N / 64, B / 64);                  // 256 x 4
    chunk_transpose_kernel<<<tgrid, 256, 0, stream>>>(x, xc);

    gather_dot_kernel<<<(N / NT) * NCHUNK, 256, 0, stream>>>(xc, w, idx, out);
}

// Round 3
// 98.022 us; speedup vs baseline: 1.3704x; 1.0095x over previous
//
#include <hip/hip_runtime.h>

// out[b,n] = relu( sum_d x[b, idx[n,d]] * w[n,d] )
//   x: (B=256, N=16384) f32, w: (N,32) f32, idx: (N,32) i32, out: (B,N) f32
//
// R3 strategy:
//   K1: x (B x N) f32 -> xc[chunk][N][32] as fp16, chunk = b/32. Each chunk is
//       1 MiB -> resident in one XCD's 4 MiB L2. Wave store = 512 B contiguous.
//   K2: block = (n-tile of 32) x (one chunk); chunk = blockIdx % 8 pins the
//       chunk to one XCD (round-robin dispatch) -> gathers are local-L2 hits.
//       fp16 halves gather traffic (512 -> 256 MiB logical). f32 accumulate;
//       error ~0.02 abs vs 0.75 threshold. Out tile transposed via padded LDS,
//       nontemporal f32 stores.

#define B      256
#define N      16384
#define DEG    32
#define NT     32        // n per block in K2
#define NCHUNK 8
#define CB     32        // b per chunk

typedef float v4f __attribute__((ext_vector_type(4)));
typedef _Float16 h4 __attribute__((ext_vector_type(4)));

__global__ __launch_bounds__(256) void chunk_transpose_f16_kernel(
    const float* __restrict__ x, _Float16* __restrict__ xc) {
    __shared__ float tile[64][65];               // [b_local][j_local], +1 pad
    const int t  = threadIdx.x;
    const int j0 = blockIdx.x * 64;              // N/64 = 256
    const int b0 = blockIdx.y * 64;              // B/64 = 4 (covers 2 chunks)
    const int c4 = t & 15;
    const int r  = t >> 4;

#pragma unroll
    for (int it = 0; it < 4; ++it) {
        const int row = r + it * 16;             // b offset in tile
        const float4 v = *(const float4*)&x[(size_t)(b0 + row) * N + j0 + 4 * c4];
        tile[row][4 * c4 + 0] = v.x;
        tile[row][4 * c4 + 1] = v.y;
        tile[row][4 * c4 + 2] = v.z;
        tile[row][4 * c4 + 3] = v.w;
    }
    __syncthreads();

    const int wv = t >> 6, l = t & 63;
    const int rl = l >> 3;                       // row-within-8
    const int a  = l & 7;                        // b4 group

#pragma unroll
    for (int it = 0; it < 4; ++it) {
        const int q  = wv * 4 + it;              // 0..15
        const int R  = q * 8 + rl;               // 0..127 = cl*64 + j_local
        const int cl = R >> 6;
        const int j  = R & 63;
        // LDS read banks: ((cl*32+4a+k)*65 + j) % 32 = (4a+k+j)%32 -> 2-way, free
        h4 h;
        h.x = (_Float16)tile[cl * 32 + 4 * a + 0][j];
        h.y = (_Float16)tile[cl * 32 + 4 * a + 1][j];
        h.z = (_Float16)tile[cl * 32 + 4 * a + 2][j];
        h.w = (_Float16)tile[cl * 32 + 4 * a + 3][j];
        // wave writes 8 consecutive j rows x 64 B = 512 B contiguous
        *(h4*)&xc[(size_t)((b0 >> 5) + cl) * N * CB + (size_t)(j0 + j) * CB + 4 * a] = h;
    }
}

__global__ __launch_bounds__(256, 8) void gather_dot_f16_kernel(
    const _Float16* __restrict__ xc, const float* __restrict__ w,
    const int* __restrict__ idx, float* __restrict__ out) {
    // 8 KiB: sidx (1024 i32) + sw (1024 f32); reused after the loop as the
    // padded out tile [NT][33].
    __shared__ __align__(16) float smem[2048];
    int*   sidx = (int*)smem;
    float* sw   = smem + NT * DEG;

    const int t     = threadIdx.x;
    const int chunk = blockIdx.x & 7;            // == XCD id under %8 round-robin
    const int nb    = (int)(blockIdx.x >> 3) * NT;
    const int wv    = t >> 6;
    const int l     = t & 63;
    const int slot  = wv * 8 + (l >> 3);         // n_local 0..31
    const int a     = l & 7;                     // b_local = 4a..4a+3

    ((int4*)sidx)[t] = ((const int4*)(idx + (size_t)nb * DEG))[t];
    ((float4*)sw)[t] = ((const float4*)(w   + (size_t)nb * DEG))[t];
    __syncthreads();

    const _Float16* xcb = xc + (size_t)chunk * N * CB + 4 * a;
    const int4*   sidx4 = (const int4*)sidx;
    const float4* sw4   = (const float4*)sw;

    float4 acc = make_float4(0.f, 0.f, 0.f, 0.f);
#pragma unroll
    for (int d4 = 0; d4 < DEG / 4; ++d4) {
        const int4   j4 = sidx4[slot * (DEG / 4) + d4];   // broadcast per 8 lanes
        const float4 w4 = sw4[slot * (DEG / 4) + d4];
        // 8 B/lane, 8 slots x 64 B contiguous rows = 512 B/wave-instr, L2-hit
        const h4 v0 = *(const h4*)&xcb[(size_t)j4.x * CB];
        const h4 v1 = *(const h4*)&xcb[(size_t)j4.y * CB];
        const h4 v2 = *(const h4*)&xcb[(size_t)j4.z * CB];
        const h4 v3 = *(const h4*)&xcb[(size_t)j4.w * CB];
        acc.x = fmaf(w4.x, (float)v0.x, acc.x); acc.y = fmaf(w4.x, (float)v0.y, acc.y);
        acc.z = fmaf(w4.x, (float)v0.z, acc.z); acc.w = fmaf(w4.x, (float)v0.w, acc.w);
        acc.x = fmaf(w4.y, (float)v1.x, acc.x); acc.y = fmaf(w4.y, (float)v1.y, acc.y);
        acc.z = fmaf(w4.y, (float)v1.z, acc.z); acc.w = fmaf(w4.y, (float)v1.w, acc.w);
        acc.x = fmaf(w4.z, (float)v2.x, acc.x); acc.y = fmaf(w4.z, (float)v2.y, acc.y);
        acc.z = fmaf(w4.z, (float)v2.z, acc.z); acc.w = fmaf(w4.z, (float)v2.w, acc.w);
        acc.x = fmaf(w4.w, (float)v3.x, acc.x); acc.y = fmaf(w4.w, (float)v3.y, acc.y);
        acc.z = fmaf(w4.w, (float)v3.z, acc.z); acc.w = fmaf(w4.w, (float)v3.w, acc.w);
    }
    __syncthreads();                             // staging dead; reuse as out tile

    float* tile = smem;                          // [NT][33]
    tile[slot * 33 + 4 * a + 0] = acc.x;
    tile[slot * 33 + 4 * a + 1] = acc.y;
    tile[slot * 33 + 4 * a + 2] = acc.z;
    tile[slot * 33 + 4 * a + 3] = acc.w;
    __syncthreads();

    const int br = wv * 8 + (l >> 3);            // b within chunk
    const int n0 = 4 * (l & 7);
    v4f v;
    v.x = fmaxf(tile[(n0 + 0) * 33 + br], 0.f);
    v.y = fmaxf(tile[(n0 + 1) * 33 + br], 0.f);
    v.z = fmaxf(tile[(n0 + 2) * 33 + br], 0.f);
    v.w = fmaxf(tile[(n0 + 3) * 33 + br], 0.f);
    __builtin_nontemporal_store(v, (v4f*)&out[(size_t)(chunk * CB + br) * N + nb + n0]);
}

extern "C" void kernel_launch(void* const* d_in, const int* in_sizes, int n_in,
                              void* d_out, int out_size, void* d_ws, size_t ws_size,
                              hipStream_t stream) {
    const float* x   = (const float*)d_in[0];    // (B, N)
    const float* w   = (const float*)d_in[1];    // (N, DEG)
    const int*   idx = (const int*)d_in[2];      // (N, DEG)
    float* out = (float*)d_out;                  // (B, N)
    _Float16* xc = (_Float16*)d_ws;              // [8][N][32] fp16 = 8 MiB

    dim3 tgrid(N / 64, B / 64);                  // 256 x 4
    chunk_transpose_f16_kernel<<<tgrid, 256, 0, stream>>>(x, xc);

    gather_dot_f16_kernel<<<(N / NT) * NCHUNK, 256, 0, stream>>>(xc, w, idx, out);
}

// Round 4
// 90.864 us; speedup vs baseline: 1.4784x; 1.0788x over previous
//
#include <hip/hip_runtime.h>

// out[b,n] = relu( sum_d x[b, idx[n,d]] * w[n,d] )
//   x: (B=256, N=16384) f32, w: (N,32) f32, idx: (N,32) i32, out: (B,N) f32
//
// R4: K2 was segment-issue-bound (R2 f32 == R3 fp16 time at equal instr and
// segment counts). Fix: gather rows = full 128-B lines (CB=64 fp16), 16 B/lane
// -> 1 KiB/instr, 8 lines/instr; instr count 524288 -> 262144, line visits
// 4M -> 2M. Staging idx/w interleaved [d4][n] kills the 8-way LDS conflicts.
//   xc[chunk=4][N][64] fp16, 2 MiB/chunk -> L2-resident per XCD
//   (chunk = blockIdx & 3; XCD = linear_block % 8 covers chunk on XCDs {c,c+4}).

#define B      256
#define N      16384
#define DEG    32
#define NT     32        // n per block in K2
#define NCHUNK 4
#define CB     64        // b per chunk (fp16 row = 128 B = one cache line)

typedef float v4f __attribute__((ext_vector_type(4)));
typedef _Float16 h8v __attribute__((ext_vector_type(8)));

__global__ __launch_bounds__(256) void chunk_transpose_f16_kernel(
    const float* __restrict__ x, _Float16* __restrict__ xc) {
    __shared__ float tile[64][65];               // [b_local][j_local], +1 pad
    const int t     = threadIdx.x;
    const int j0    = blockIdx.x * 64;           // N/64 = 256
    const int chunk = blockIdx.y;                // b0 = chunk*64 (B/64 = 4)
    const int c4 = t & 15;
    const int r  = t >> 4;

#pragma unroll
    for (int it = 0; it < 4; ++it) {
        const int row = r + it * 16;             // b_local
        const float4 v = *(const float4*)&x[(size_t)(chunk * 64 + row) * N + j0 + 4 * c4];
        tile[row][4 * c4 + 0] = v.x;
        tile[row][4 * c4 + 1] = v.y;
        tile[row][4 * c4 + 2] = v.z;
        tile[row][4 * c4 + 3] = v.w;
    }
    __syncthreads();

    const int wv = t >> 6, l = t & 63;
    const int a  = l & 7;                        // b-octet: b = 8a..8a+7
    _Float16* dst = xc + (size_t)chunk * N * CB + 8 * a;
#pragma unroll
    for (int p = 0; p < 2; ++p) {
        const int j = p * 32 + wv * 8 + (l >> 3);
        // LDS banks: (8a+k + j) % 32 over a,j lanes -> 2-way, free
        h8v h;
#pragma unroll
        for (int k = 0; k < 8; ++k) h[k] = (_Float16)tile[8 * a + k][j];
        // wave: 8 consecutive j rows x 128 B = 1 KiB fully contiguous
        *(h8v*)&dst[(size_t)(j0 + j) * CB] = h;
    }
}

__global__ __launch_bounds__(256, 8) void gather_dot_f16_kernel(
    const _Float16* __restrict__ xc, const float* __restrict__ w,
    const int* __restrict__ idx, float* __restrict__ out) {
    // staging: sidx 1024 i32 + sw 1024 f32 (8 KiB), interleaved [d4][n];
    // reused after the loop as out tile [b=64][n pad 33] = 8448 B.
    __shared__ __align__(16) float smem[64 * 33];
    int*   sidx = (int*)smem;
    float* sw   = smem + 1024;

    const int t     = threadIdx.x;
    const int chunk = blockIdx.x & 3;
    const int nb    = (int)(blockIdx.x >> 2) * NT;
    const int wv    = t >> 6;
    const int l     = t & 63;
    const int slot  = wv * 8 + (l >> 3);         // n_local 0..31
    const int a     = l & 7;                     // b-octet: b = 8a..8a+7

    // Stage idx/w interleaved: element (n,d4) -> [d4*32 + n]
    {
        const int n_l = t >> 3, d4 = t & 7;
        ((int4*)sidx)[d4 * 32 + n_l] = ((const int4*)(idx + (size_t)nb * DEG))[t];
        ((float4*)sw)[d4 * 32 + n_l] = ((const float4*)(w + (size_t)nb * DEG))[t];
    }
    __syncthreads();

    const _Float16* xcb = xc + (size_t)chunk * N * CB + 8 * a;

    float acc[8] = {0.f, 0.f, 0.f, 0.f, 0.f, 0.f, 0.f, 0.f};
#pragma unroll
    for (int d4 = 0; d4 < DEG / 4; ++d4) {
        // 8 distinct consecutive 16-B words -> all 32 banks, conflict-free
        const int4   j4 = ((const int4*)sidx)[d4 * 32 + slot];
        const float4 w4 = ((const float4*)sw)[d4 * 32 + slot];
        // each: 8 slot-groups x one full 128-B line = 1 KiB/wave-instr
        const h8v v0 = *(const h8v*)&xcb[(size_t)j4.x * CB];
        const h8v v1 = *(const h8v*)&xcb[(size_t)j4.y * CB];
        const h8v v2 = *(const h8v*)&xcb[(size_t)j4.z * CB];
        const h8v v3 = *(const h8v*)&xcb[(size_t)j4.w * CB];
#pragma unroll
        for (int k = 0; k < 8; ++k) acc[k] = fmaf(w4.x, (float)v0[k], acc[k]);
#pragma unroll
        for (int k = 0; k < 8; ++k) acc[k] = fmaf(w4.y, (float)v1[k], acc[k]);
#pragma unroll
        for (int k = 0; k < 8; ++k) acc[k] = fmaf(w4.z, (float)v2[k], acc[k]);
#pragma unroll
        for (int k = 0; k < 8; ++k) acc[k] = fmaf(w4.w, (float)v3[k], acc[k]);
    }
    __syncthreads();                             // staging dead; reuse as out tile

    float* tile = smem;                          // [b=64][pad 33]
#pragma unroll
    for (int k = 0; k < 8; ++k)
        tile[(8 * a + k) * 33 + slot] = acc[k];  // banks (8a+k+slot)%32: 2-way
    __syncthreads();

#pragma unroll
    for (int p = 0; p < 2; ++p) {
        const int b = wv * 16 + p * 8 + (l >> 3);
        const int c = l & 7;
        v4f v;
        v.x = fmaxf(tile[b * 33 + 4 * c + 0], 0.f);
        v.y = fmaxf(tile[b * 33 + 4 * c + 1], 0.f);
        v.z = fmaxf(tile[b * 33 + 4 * c + 2], 0.f);
        v.w = fmaxf(tile[b * 33 + 4 * c + 3], 0.f);
        // 8 lanes x 16 B = 128 B contiguous per b-row
        __builtin_nontemporal_store(v, (v4f*)&out[(size_t)(chunk * CB + b) * N + nb + 4 * c]);
    }
}

extern "C" void kernel_launch(void* const* d_in, const int* in_sizes, int n_in,
                              void* d_out, int out_size, void* d_ws, size_t ws_size,
                              hipStream_t stream) {
    const float* x   = (const float*)d_in[0];    // (B, N)
    const float* w   = (const float*)d_in[1];    // (N, DEG)
    const int*   idx = (const int*)d_in[2];      // (N, DEG)
    float* out = (float*)d_out;                  // (B, N)
    _Float16* xc = (_Float16*)d_ws;              // [4][N][64] fp16 = 8 MiB

    dim3 tgrid(N / 64, B / 64);                  // 256 x 4
    chunk_transpose_f16_kernel<<<tgrid, 256, 0, stream>>>(x, xc);

    gather_dot_f16_kernel<<<(N / NT) * NCHUNK, 256, 0, stream>>>(xc, w, idx, out);
}